// Round 8
// baseline (493.677 us; speedup 1.0000x reference)
//
#include <hip/hip_runtime.h>
#include <hip/hip_bf16.h>

#define S_LEN  2048
#define BATCH  4
#define DIM    1024
#define NSTATE 256
#define DFF    2730
#define DFFP   2752              // K-padding for final GEMM (mult of 64)
#define DFQ    2816              // row-padding for w1/w2 (mult of 128)
#define NROWS  (BATCH * S_LEN)   // 8192
#define LC     8                 // scan chunk length (r7: 16->8, 4 blocks/CU)
#define WARM   32                // scan warm-up window (decay ~e^-13 worst)
#define NBG    384               // WB(256) + Wg(32) + zero pad(96)

// prep_kernel block-range offsets (r6: fused prep; r7: +counter zeroing)
#define PB_CAYLEY 0                         // 32 blocks
#define PB_WBG    (PB_CAYLEY + 32)          // 384
#define PB_WC     (PB_WBG + NBG)            // 256
#define PB_W1     (PB_WC + 256)             // 2816
#define PB_W2     (PB_W1 + DFQ)             // 2816
#define PB_W3     (PB_W2 + DFQ)             // 11264
#define PB_RMS    (PB_W3 + 11 * DIM)        // 8192
#define PB_ZC     (PB_RMS + NROWS)          // 1 (zero stripe counters)
#define PB_TOTAL  (PB_ZC + 1)               // 25761

typedef __attribute__((ext_vector_type(8))) short bf16x8;
typedef __attribute__((ext_vector_type(4))) float f32x4;

__device__ __forceinline__ float bf2f(ushort u) {
    return __uint_as_float(((unsigned int)u) << 16);
}
__device__ __forceinline__ ushort f2bf(float f) {
    unsigned int u = __float_as_uint(f);
    u += 0x7fffu + ((u >> 16) & 1u);   // RNE
    return (ushort)(u >> 16);
}

// async global->LDS, 16B per lane. LDS dest is wave-uniform base + lane*16.
__device__ __forceinline__ void gld_lds16(const ushort* g, ushort* l) {
    __builtin_amdgcn_global_load_lds(
        (const __attribute__((address_space(1))) unsigned int*)g,
        (__attribute__((address_space(3))) unsigned int*)l,
        16, 0, 0);
}

// ---------------------------------------------------------------------------
// Unified prep kernel: cayley | pack_wbg | f2b(WC) | padrow(w1) | padrow(w2)
// | pad_w3 | rmsnorm1 | zero-counters. One launch replaces 7 (r6: -17us).
// ---------------------------------------------------------------------------
__global__ __launch_bounds__(256) void prep_kernel(
    const float* __restrict__ Lsk, const float* __restrict__ Rsk,
    float* __restrict__ QL, float* __restrict__ QR,
    const float* __restrict__ WB, const float* __restrict__ Wg,
    ushort* __restrict__ WBGb,
    const float* __restrict__ WC, ushort* __restrict__ WCb,
    const float* __restrict__ w1, ushort* __restrict__ w1p,
    const float* __restrict__ w2, ushort* __restrict__ w2p,
    const float* __restrict__ w3, ushort* __restrict__ w3p,
    const float* __restrict__ x, const float* __restrict__ n1w,
    ushort* __restrict__ xs, int* __restrict__ cnt)
{
    const int bid = blockIdx.x, t = threadIdx.x;

    if (bid < PB_WBG) {                       // ---- cayley (32 blocks)
        __shared__ float Ms[16][17];
        __shared__ float Rh[16][17];
        const int m = bid;
        const float* src = (m < 16) ? (Lsk + m * 256) : (Rsk + (m - 16) * 256);
        const int i = t >> 4, j = t & 15;
        float a = src[i * 16 + j] - src[j * 16 + i];
        float eye = (i == j) ? 1.f : 0.f;
        Ms[i][j] = eye + a;
        Rh[i][j] = eye - a;
        __syncthreads();
        for (int k = 0; k < 16; ++k) {
            float f = Ms[i][k] / Ms[k][k];
            __syncthreads();
            if (i != k) {
                Ms[i][j] -= f * Ms[k][j];
                Rh[i][j] -= f * Rh[k][j];
            }
            __syncthreads();
        }
        float q = Rh[i][j] / Ms[i][i];
        float* dst = (m < 16) ? (QL + m * 256) : (QR + (m - 16) * 256);
        dst[i * 16 + j] = q;
    } else if (bid < PB_WC) {                 // ---- pack_wbg (384 blocks)
        const int row = bid - PB_WBG;
        ushort4 o = {0, 0, 0, 0};
        const float* src = nullptr;
        if (row < NSTATE) src = WB + (size_t)row * DIM;
        else if (row < NSTATE + 32) src = Wg + (size_t)(row - NSTATE) * DIM;
        if (src) {
            float4 v = *(const float4*)(src + t * 4);
            o.x = f2bf(v.x); o.y = f2bf(v.y); o.z = f2bf(v.z); o.w = f2bf(v.w);
        }
        *(ushort4*)(WBGb + (size_t)row * DIM + t * 4) = o;
    } else if (bid < PB_W1) {                 // ---- f2b WC (256 blocks)
        const int i = (bid - PB_WC) * 256 + t;     // covers DIM*NSTATE/4 exactly
        float4 v = *(const float4*)(WC + i * 4);
        ushort4 o;
        o.x = f2bf(v.x); o.y = f2bf(v.y); o.z = f2bf(v.z); o.w = f2bf(v.w);
        *(ushort4*)(WCb + i * 4) = o;
    } else if (bid < PB_W2) {                 // ---- padrow w1 (2816 blocks)
        const int row = bid - PB_W1;
        ushort4 o = {0, 0, 0, 0};
        if (row < DFF) {
            float4 v = *(const float4*)(w1 + (size_t)row * DIM + t * 4);
            o.x = f2bf(v.x); o.y = f2bf(v.y); o.z = f2bf(v.z); o.w = f2bf(v.w);
        }
        *(ushort4*)(w1p + (size_t)row * DIM + t * 4) = o;
    } else if (bid < PB_W3) {                 // ---- padrow w2 (2816 blocks)
        const int row = bid - PB_W2;
        ushort4 o = {0, 0, 0, 0};
        if (row < DFF) {
            float4 v = *(const float4*)(w2 + (size_t)row * DIM + t * 4);
            o.x = f2bf(v.x); o.y = f2bf(v.y); o.z = f2bf(v.z); o.w = f2bf(v.w);
        }
        *(ushort4*)(w2p + (size_t)row * DIM + t * 4) = o;
    } else if (bid < PB_RMS) {                // ---- pad_w3 (11264 blocks)
        const int lid = bid - PB_W3;
        const int row = lid / 11, cb = lid % 11;
        const int col = cb * 256 + t;
        if (col < DFFP) {
            ushort v = 0;
            if (col < DFF) v = f2bf(w3[(size_t)row * DFF + col]);
            w3p[(size_t)row * DFFP + col] = v;
        }
    } else if (bid < PB_ZC) {                 // ---- rmsnorm1 (8192 blocks)
        __shared__ float part[4];
        __shared__ float invs;
        const int row = bid - PB_RMS;
        float4 xv = *(const float4*)(x + (size_t)row * DIM + t * 4);
        float ss = xv.x * xv.x + xv.y * xv.y + xv.z * xv.z + xv.w * xv.w;
        for (int off = 32; off > 0; off >>= 1) ss += __shfl_down(ss, off, 64);
        if ((t & 63) == 0) part[t >> 6] = ss;
        __syncthreads();
        if (t == 0) {
            float tot = part[0] + part[1] + part[2] + part[3];
            invs = 1.f / sqrtf(tot / (float)DIM + 1e-6f);
        }
        __syncthreads();
        float inv = invs;
        float4 wv = *(const float4*)(n1w + t * 4);
        ushort4 ov;
        ov.x = f2bf(wv.x * xv.x * inv);
        ov.y = f2bf(wv.y * xv.y * inv);
        ov.z = f2bf(wv.z * xv.z * inv);
        ov.w = f2bf(wv.w * xv.w * inv);
        *(ushort4*)(xs + (size_t)row * DIM + t * 4) = ov;
    } else {                                  // ---- zero stripe counters (1)
        if (t < 64) cnt[t] = 0;               // re-zeroed every invocation
    }
}

// ---------------------------------------------------------------------------
// Windowed parallel scan. LC=8 -> 1024 blocks = 4/CU (r7, was 2/CU).
// One barrier/step: Hs deps are intra-wave; Us double-buffered; raw
// lgkmcnt+s_barrier avoids the vmcnt(0) drain.
// ---------------------------------------------------------------------------
__global__ __launch_bounds__(256) void scan_win_kernel(
    const float* __restrict__ QL, const float* __restrict__ QR,
    const float* __restrict__ gates, const float* __restrict__ Bx,
    ushort* __restrict__ hs)
{
    __shared__ float Hs[256];
    __shared__ float Us[2][256];
    const int chunk = blockIdx.x, b = blockIdx.y, t = threadIdx.x;
    const int hi = t >> 4, lo = t & 15;
    float Rrow[16], Lrow[16];
    #pragma unroll
    for (int k = 0; k < 16; ++k) {
        Rrow[k] = QR[hi * 256 + lo * 16 + k];   // R_Q[j=hi][i=lo][k]
        Lrow[k] = QL[lo * 256 + hi * 16 + k];   // L_Q[c=lo][r=hi][k]
    }
    Hs[t] = 0.f;
    __syncthreads();
    const int wstart = chunk * LC;
    const int s0 = (wstart >= WARM) ? (wstart - WARM) : 0;
    const int send = wstart + LC;
    const float* gb = gates + (size_t)b * S_LEN * 32;
    const float* xb = Bx + (size_t)b * S_LEN * NSTATE;
    ushort* hb = hs + (size_t)b * S_LEN * NSTATE;
    float beta  = gb[s0 * 32 + 16 + hi];
    float alpha = gb[s0 * 32 + lo];
    float bx    = xb[s0 * NSTATE + t];
    int q = 0;
    for (int s = s0; s < send; ++s) {
        float betaN = 0.f, alphaN = 0.f, bxN = 0.f;
        if (s + 1 < send) {
            betaN  = gb[(s + 1) * 32 + 16 + hi];
            alphaN = gb[(s + 1) * 32 + lo];
            bxN    = xb[(s + 1) * NSTATE + t];
        }
        float acc = 0.f;
        #pragma unroll
        for (int k = 0; k < 16; ++k) acc += Rrow[k] * Hs[hi * 16 + k];
        Us[q][t] = beta * acc;
        asm volatile("s_waitcnt lgkmcnt(0)" ::: "memory");
        __builtin_amdgcn_s_barrier();
        asm volatile("" ::: "memory");
        float acc2 = 0.f;
        #pragma unroll
        for (int k = 0; k < 16; ++k) acc2 += Lrow[k] * Us[q][k * 16 + lo];
        float h = alpha * acc2 + bx;
        Hs[t] = h;                       // intra-wave consumers only
        if (s >= wstart) hb[s * NSTATE + t] = f2bf(h);
        beta = betaN; alpha = alphaN; bx = bxN;
        q ^= 1;
    }
}

// ---------------------------------------------------------------------------
// Async GEMM: C(MxN) = A(MxK)*B(NxK)^T [+bias +resF] -> fp32.
// 128x128 tile, BK=64, XOR-8 LDS swizzle, 4 waves (2x2 of 64x64),
// 16x16x32 bf16 MFMA, global_load_lds width-16 staging.
// r7: optional fused rms tail (cnt/nw/xo non-null): split-K-finisher pattern.
// Each block fences + bumps its row-stripe counter; the 8th block re-reads
// the stripe (L2-hot) and does a wave-parallel rmsnorm (32 rows/wave, pure
// intra-wave shuffle reduce, no barriers). Saves the separate rms launch and
// its 33MB HBM re-read of x2.
// ---------------------------------------------------------------------------
__global__ __launch_bounds__(256) void gemm_async(
    const ushort* __restrict__ A, int lda,
    const ushort* __restrict__ B, int ldb,
    int K, int ldc,
    const float* __restrict__ bias,
    const float* __restrict__ resF,
    float* __restrict__ outF,
    int* __restrict__ cnt,               // non-null => fused rms tail
    const float* __restrict__ nw,
    ushort* __restrict__ xo)
{
    __shared__ ushort As[128 * 64];
    __shared__ ushort Bs[128 * 64];
    const int tid = threadIdx.x;
    const int m0 = blockIdx.y * 128, n0 = blockIdx.x * 128;
    const int w = tid >> 6, lane = tid & 63;
    const int wm = (w >> 1) * 64, wn = (w & 1) * 64;
    const int lr = lane & 15, quad = lane >> 4;
    const int rx = lr & 7;   // reader XOR key (row&7 of every frag row)
    f32x4 acc[4][4];
    #pragma unroll
    for (int i = 0; i < 4; ++i)
        #pragma unroll
        for (int j = 0; j < 4; ++j) acc[i][j] = (f32x4){0.f, 0.f, 0.f, 0.f};
    const int srow = tid >> 3;                              // 0..31
    const int scol = (((tid & 7) ^ (srow & 7)) * 8);        // swizzled fetch col
    const ushort* ga = A + (size_t)(m0 + srow) * lda + scol;
    const ushort* gb = B + (size_t)(n0 + srow) * ldb + scol;
    for (int kt = 0; kt < K; kt += 64) {
        #pragma unroll
        for (int p = 0; p < 4; ++p) {
            gld_lds16(ga + (size_t)(p * 32) * lda + kt, &As[p * 2048 + tid * 8]);
            gld_lds16(gb + (size_t)(p * 32) * ldb + kt, &Bs[p * 2048 + tid * 8]);
        }
        __syncthreads();
        #pragma unroll
        for (int s = 0; s < 2; ++s) {
            const int cg = ((s * 4 + quad) ^ rx) * 8;
            bf16x8 af[4], bfr[4];
            #pragma unroll
            for (int f = 0; f < 4; ++f) {
                af[f]  = *(const bf16x8*)&As[(wm + f * 16 + lr) * 64 + cg];
                bfr[f] = *(const bf16x8*)&Bs[(wn + f * 16 + lr) * 64 + cg];
            }
            #pragma unroll
            for (int i = 0; i < 4; ++i)
                #pragma unroll
                for (int j = 0; j < 4; ++j)
                    acc[i][j] = __builtin_amdgcn_mfma_f32_16x16x32_bf16(
                        af[i], bfr[j], acc[i][j], 0, 0, 0);
        }
        __syncthreads();
    }
    #pragma unroll
    for (int i = 0; i < 4; ++i) {
        int row = m0 + wm + i * 16 + quad * 4;
        #pragma unroll
        for (int j = 0; j < 4; ++j) {
            int col = n0 + wn + j * 16 + lr;
            float bv = bias ? bias[col] : 0.f;
            #pragma unroll
            for (int r = 0; r < 4; ++r) {
                size_t idx = (size_t)(row + r) * ldc + col;
                float v = acc[i][j][r] + bv;
                if (resF) v += resF[idx];
                outF[idx] = v;
            }
        }
    }
    // ---- fused rms tail (gemm1 only): last block of the row-stripe does it
    if (cnt) {
        __threadfence();                       // release: x2 tile visible
        __shared__ int oldc;
        if (tid == 0) oldc = atomicAdd(&cnt[blockIdx.y], 1);
        __syncthreads();
        if (oldc == (int)gridDim.x - 1) {
            __threadfence();                   // acquire: others' tiles visible
            const int wv = tid >> 6;
            const float* base = outF + (size_t)m0 * ldc;
            for (int r = wv * 32; r < wv * 32 + 32; ++r) {
                const float* rp = base + (size_t)r * ldc;
                float4 v[4];
                float ss = 0.f;
                #pragma unroll
                for (int c = 0; c < 4; ++c) {
                    v[c] = *(const float4*)(rp + lane * 4 + c * 256);
                    ss += v[c].x * v[c].x + v[c].y * v[c].y
                        + v[c].z * v[c].z + v[c].w * v[c].w;
                }
                for (int off = 32; off > 0; off >>= 1)
                    ss += __shfl_down(ss, off, 64);
                ss = __shfl(ss, 0, 64);
                float inv = 1.f / sqrtf(ss / (float)DIM + 1e-6f);
                #pragma unroll
                for (int c = 0; c < 4; ++c) {
                    float4 wv4 = *(const float4*)(nw + lane * 4 + c * 256);
                    ushort4 o;
                    o.x = f2bf(wv4.x * v[c].x * inv);
                    o.y = f2bf(wv4.y * v[c].y * inv);
                    o.z = f2bf(wv4.z * v[c].z * inv);
                    o.w = f2bf(wv4.w * v[c].w * inv);
                    *(ushort4*)(xo + (size_t)(m0 + r) * DIM + lane * 4 + c * 256) = o;
                }
            }
        }
    }
}

// ---------------------------------------------------------------------------
// Merged Bx+gates GEMM: [Bx | gate-logits] = xs @ WBG^T, N=384, BK=64+swizzle.
// ---------------------------------------------------------------------------
__global__ __launch_bounds__(256) void gemm_bxg(
    const ushort* __restrict__ A,     // xs: NROWS x DIM
    const ushort* __restrict__ WBG,   // NBG x DIM
    const float* __restrict__ bB, const float* __restrict__ bg,
    float* __restrict__ Bx, float* __restrict__ gates)
{
    __shared__ ushort As[128 * 64];
    __shared__ ushort Bs[128 * 64];
    const int tid = threadIdx.x;
    const int m0 = blockIdx.y * 128, n0 = blockIdx.x * 128;
    const int w = tid >> 6, lane = tid & 63;
    const int wm = (w >> 1) * 64, wn = (w & 1) * 64;
    const int lr = lane & 15, quad = lane >> 4;
    const int rx = lr & 7;
    f32x4 acc[4][4];
    #pragma unroll
    for (int i = 0; i < 4; ++i)
        #pragma unroll
        for (int j = 0; j < 4; ++j) acc[i][j] = (f32x4){0.f, 0.f, 0.f, 0.f};
    const int srow = tid >> 3;
    const int scol = (((tid & 7) ^ (srow & 7)) * 8);
    const ushort* ga = A   + (size_t)(m0 + srow) * DIM + scol;
    const ushort* gb = WBG + (size_t)(n0 + srow) * DIM + scol;
    for (int kt = 0; kt < DIM; kt += 64) {
        #pragma unroll
        for (int p = 0; p < 4; ++p) {
            gld_lds16(ga + (size_t)(p * 32) * DIM + kt, &As[p * 2048 + tid * 8]);
            gld_lds16(gb + (size_t)(p * 32) * DIM + kt, &Bs[p * 2048 + tid * 8]);
        }
        __syncthreads();
        #pragma unroll
        for (int s = 0; s < 2; ++s) {
            const int cg = ((s * 4 + quad) ^ rx) * 8;
            bf16x8 af[4], bfr[4];
            #pragma unroll
            for (int f = 0; f < 4; ++f) {
                af[f]  = *(const bf16x8*)&As[(wm + f * 16 + lr) * 64 + cg];
                bfr[f] = *(const bf16x8*)&Bs[(wn + f * 16 + lr) * 64 + cg];
            }
            #pragma unroll
            for (int i = 0; i < 4; ++i)
                #pragma unroll
                for (int j = 0; j < 4; ++j)
                    acc[i][j] = __builtin_amdgcn_mfma_f32_16x16x32_bf16(
                        af[i], bfr[j], acc[i][j], 0, 0, 0);
        }
        __syncthreads();
    }
    #pragma unroll
    for (int i = 0; i < 4; ++i) {
        int row = m0 + wm + i * 16 + quad * 4;
        #pragma unroll
        for (int j = 0; j < 4; ++j) {
            int col = n0 + wn + j * 16 + lr;
            #pragma unroll
            for (int r = 0; r < 4; ++r) {
                float v = acc[i][j][r];
                if (col < NSTATE) {
                    Bx[(size_t)(row + r) * NSTATE + col] = v + bB[col];
                } else if (col < NSTATE + 32) {
                    int g = col - NSTATE;
                    gates[(size_t)(row + r) * 32 + g] =
                        1.f / (1.f + expf(-(v + bg[g])));
                }
            }
        }
    }
}

// ---------------------------------------------------------------------------
// Fused FFN GEMM: pb = bf16( silu(xn@w1^T) * (xn@w2^T) ), K-padded layout.
// BK=64 + XOR-8 swizzle; A staged once, two B tiles -> 64 MFMA per barrier
// round. [2-barrier structure = its structural ceiling at ~108us/875TF;
// 8-phase port abandoned after 3 attempts (r2 remat / r3 spills / r5
// LDS+barrier-bound).]
// ---------------------------------------------------------------------------
__global__ __launch_bounds__(256, 2) void ffn_gemm(
    const ushort* __restrict__ A,    // xn: NROWS x DIM
    const ushort* __restrict__ B1,   // w1p: DFQ x DIM
    const ushort* __restrict__ B2,   // w2p: DFQ x DIM
    ushort* __restrict__ pb)         // NROWS x DFFP
{
    __shared__ ushort As [128 * 64];
    __shared__ ushort B1s[128 * 64];
    __shared__ ushort B2s[128 * 64];
    const int tid = threadIdx.x;
    const int m0 = blockIdx.y * 128, n0 = blockIdx.x * 128;
    const int w = tid >> 6, lane = tid & 63;
    const int wm = (w >> 1) * 64, wn = (w & 1) * 64;
    const int lr = lane & 15, quad = lane >> 4;
    const int rx = lr & 7;
    f32x4 acc1[4][4], acc2[4][4];
    #pragma unroll
    for (int i = 0; i < 4; ++i)
        #pragma unroll
        for (int j = 0; j < 4; ++j) {
            acc1[i][j] = (f32x4){0.f, 0.f, 0.f, 0.f};
            acc2[i][j] = (f32x4){0.f, 0.f, 0.f, 0.f};
        }
    const int srow = tid >> 3;
    const int scol = (((tid & 7) ^ (srow & 7)) * 8);
    const ushort* ga  = A  + (size_t)(m0 + srow) * DIM + scol;
    const ushort* gb1 = B1 + (size_t)(n0 + srow) * DIM + scol;
    const ushort* gb2 = B2 + (size_t)(n0 + srow) * DIM + scol;
    for (int kt = 0; kt < DIM; kt += 64) {
        #pragma unroll
        for (int p = 0; p < 4; ++p) {
            gld_lds16(ga  + (size_t)(p * 32) * DIM + kt, &As [p * 2048 + tid * 8]);
            gld_lds16(gb1 + (size_t)(p * 32) * DIM + kt, &B1s[p * 2048 + tid * 8]);
            gld_lds16(gb2 + (size_t)(p * 32) * DIM + kt, &B2s[p * 2048 + tid * 8]);
        }
        __syncthreads();
        #pragma unroll
        for (int s = 0; s < 2; ++s) {
            const int cg = ((s * 4 + quad) ^ rx) * 8;
            bf16x8 af[4], b1f[4], b2f[4];
            #pragma unroll
            for (int f = 0; f < 4; ++f) {
                af[f]  = *(const bf16x8*)&As [(wm + f * 16 + lr) * 64 + cg];
                b1f[f] = *(const bf16x8*)&B1s[(wn + f * 16 + lr) * 64 + cg];
                b2f[f] = *(const bf16x8*)&B2s[(wn + f * 16 + lr) * 64 + cg];
            }
            #pragma unroll
            for (int i = 0; i < 4; ++i)
                #pragma unroll
                for (int j = 0; j < 4; ++j) {
                    acc1[i][j] = __builtin_amdgcn_mfma_f32_16x16x32_bf16(
                        af[i], b1f[j], acc1[i][j], 0, 0, 0);
                    acc2[i][j] = __builtin_amdgcn_mfma_f32_16x16x32_bf16(
                        af[i], b2f[j], acc2[i][j], 0, 0, 0);
                }
        }
        __syncthreads();
    }
    #pragma unroll
    for (int i = 0; i < 4; ++i) {
        int row = m0 + wm + i * 16 + quad * 4;
        #pragma unroll
        for (int j = 0; j < 4; ++j) {
            int col = n0 + wn + j * 16 + lr;
            if (col < DFFP) {
                #pragma unroll
                for (int r = 0; r < 4; ++r) {
                    float v1 = acc1[i][j][r];
                    float v2 = acc2[i][j][r];
                    float p = v1 / (1.f + expf(-v1)) * v2;
                    pb[(size_t)(row + r) * DFFP + col] = f2bf(p);
                }
            }
        }
    }
}

// ---------------------------------------------------------------------------
extern "C" void kernel_launch(void* const* d_in, const int* in_sizes, int n_in,
                              void* d_out, int out_size, void* d_ws, size_t ws_size,
                              hipStream_t stream) {
    const float* x   = (const float*)d_in[0];
    const float* Lsk = (const float*)d_in[1];
    const float* Rsk = (const float*)d_in[2];
    const float* Wg  = (const float*)d_in[3];
    const float* bg  = (const float*)d_in[4];
    const float* WB  = (const float*)d_in[5];
    const float* bB  = (const float*)d_in[6];
    const float* WC  = (const float*)d_in[7];
    const float* bC  = (const float*)d_in[8];
    const float* n1w = (const float*)d_in[9];
    const float* n2w = (const float*)d_in[10];
    const float* w1  = (const float*)d_in[11];
    const float* w2  = (const float*)d_in[12];
    const float* w3  = (const float*)d_in[13];
    float* out = (float*)d_out;

    char* wp = (char*)d_ws;
    auto carve = [&](size_t bytes) -> char* {
        char* p = wp;
        wp += (bytes + 255) & ~(size_t)255;
        return p;
    };
    float*  QL    = (float*)carve(16 * 256 * 4);
    float*  QR    = (float*)carve(16 * 256 * 4);
    int*    cnt   = (int*)carve(64 * 4);
    ushort* WBGb  = (ushort*)carve((size_t)NBG * DIM * 2);
    ushort* WCb   = (ushort*)carve((size_t)DIM * NSTATE * 2);
    ushort* w1p   = (ushort*)carve((size_t)DFQ * DIM * 2);
    ushort* w2p   = (ushort*)carve((size_t)DFQ * DIM * 2);
    ushort* w3p   = (ushort*)carve((size_t)DIM * DFFP * 2);
    ushort* xs    = (ushort*)carve((size_t)NROWS * DIM * 2);
    float*  x2    = (float*)carve((size_t)NROWS * DIM * 4);
    ushort* pb    = (ushort*)carve((size_t)NROWS * DFFP * 2);
    char*   scr   = carve((size_t)16 << 20);                // gates/Bx/hs region
    float*  gates = (float*)scr;                            // 1.05 MB
    float*  Bx    = (float*)(scr + (1 << 21));              // 8.39 MB @ +2MB
    ushort* hs    = (ushort*)(scr + (11u << 20));           // 4.19 MB @ +11MB
    ushort* xn    = xs;   // xs dead after bxg GEMM; reuse as xn

    // all weight prep + cayley + rmsnorm1 + counter-zeroing in ONE launch
    prep_kernel<<<PB_TOTAL, 256, 0, stream>>>(
        Lsk, Rsk, QL, QR, WB, Wg, WBGb, WC, WCb,
        w1, w1p, w2, w2p, w3, w3p, x, n1w, xs, cnt);
    // [Bx | gates] = xs @ WBG^T (+bB | sigmoid(+bg))
    gemm_bxg<<<dim3(3, 64), 256, 0, stream>>>(xs, WBGb, bB, bg, Bx, gates);
    scan_win_kernel<<<dim3(S_LEN / LC, BATCH), 256, 0, stream>>>(QL, QR, gates, Bx, hs);
    // x2 = hs @ WC^T + bC + x -> fp32, FUSED rms tail -> xn (launch saved)
    gemm_async<<<dim3(8, 64), 256, 0, stream>>>(hs, NSTATE, WCb, NSTATE, NSTATE, DIM,
                                                bC, x, x2, cnt, n2w, xn);
    // pb = silu(xn@w1^T) * (xn@w2^T)  (fused, K-padded bf16 out)
    ffn_gemm<<<dim3(DFQ / 128, 64), 256, 0, stream>>>(xn, w1p, w2p, pb);
    // out = pb @ w3p^T + x2  -> fp32 (d_out)
    gemm_async<<<dim3(8, 64), 256, 0, stream>>>(pb, DFFP, w3p, DFFP, DFFP, DIM,
                                                nullptr, x2, out, nullptr, nullptr, nullptr);
}

// Round 9
// 413.644 us; speedup vs baseline: 1.1935x; 1.1935x over previous
//
#include <hip/hip_runtime.h>
#include <hip/hip_bf16.h>

#define S_LEN  2048
#define BATCH  4
#define DIM    1024
#define NSTATE 256
#define DFF    2730
#define DFFP   2752              // K-padding for final GEMM (mult of 64)
#define DFQ    2816              // row-padding for w1/w2 (mult of 128)
#define NROWS  (BATCH * S_LEN)   // 8192
#define LC     8                 // scan chunk length (4 blocks/CU)
#define WARM   32                // scan warm-up window (decay ~e^-13 worst)
#define NBG    384               // WB(256) + Wg(32) + zero pad(96)

// prep_kernel block-range offsets (r6: fuse 7 launches into 1)
#define PB_CAYLEY 0                         // 32 blocks
#define PB_WBG    (PB_CAYLEY + 32)          // 384
#define PB_WC     (PB_WBG + NBG)            // 256
#define PB_W1     (PB_WC + 256)             // 2816
#define PB_W2     (PB_W1 + DFQ)             // 2816
#define PB_W3     (PB_W2 + DFQ)             // 11264
#define PB_RMS    (PB_W3 + 11 * DIM)        // 8192
#define PB_TOTAL  (PB_RMS + NROWS)          // 25760

typedef __attribute__((ext_vector_type(8))) short bf16x8;
typedef __attribute__((ext_vector_type(4))) float f32x4;

__device__ __forceinline__ float bf2f(ushort u) {
    return __uint_as_float(((unsigned int)u) << 16);
}
__device__ __forceinline__ ushort f2bf(float f) {
    unsigned int u = __float_as_uint(f);
    u += 0x7fffu + ((u >> 16) & 1u);   // RNE
    return (ushort)(u >> 16);
}

// async global->LDS, 16B per lane. LDS dest is wave-uniform base + lane*16.
__device__ __forceinline__ void gld_lds16(const ushort* g, ushort* l) {
    __builtin_amdgcn_global_load_lds(
        (const __attribute__((address_space(1))) unsigned int*)g,
        (__attribute__((address_space(3))) unsigned int*)l,
        16, 0, 0);
}

// ---------------------------------------------------------------------------
// Unified prep kernel: cayley | pack_wbg | f2b(WC) | padrow(w1) | padrow(w2)
// | pad_w3 | rmsnorm1. One launch replaces 7 (r6 win).
// [r8 journal: fused rms-into-gemm tail via atomicAdd+__threadfence was a
//  10x regression (137us, MfmaUtil 1.2%) -- device-scope fences on CDNA4
//  flush/invalidate per-XCD L2; cross-block sync inside one launch is an
//  anti-pattern here. Separate rms launch restored.]
// ---------------------------------------------------------------------------
__global__ __launch_bounds__(256) void prep_kernel(
    const float* __restrict__ Lsk, const float* __restrict__ Rsk,
    float* __restrict__ QL, float* __restrict__ QR,
    const float* __restrict__ WB, const float* __restrict__ Wg,
    ushort* __restrict__ WBGb,
    const float* __restrict__ WC, ushort* __restrict__ WCb,
    const float* __restrict__ w1, ushort* __restrict__ w1p,
    const float* __restrict__ w2, ushort* __restrict__ w2p,
    const float* __restrict__ w3, ushort* __restrict__ w3p,
    const float* __restrict__ x, const float* __restrict__ n1w,
    ushort* __restrict__ xs)
{
    const int bid = blockIdx.x, t = threadIdx.x;

    if (bid < PB_WBG) {                       // ---- cayley (32 blocks)
        __shared__ float Ms[16][17];
        __shared__ float Rh[16][17];
        const int m = bid;
        const float* src = (m < 16) ? (Lsk + m * 256) : (Rsk + (m - 16) * 256);
        const int i = t >> 4, j = t & 15;
        float a = src[i * 16 + j] - src[j * 16 + i];
        float eye = (i == j) ? 1.f : 0.f;
        Ms[i][j] = eye + a;
        Rh[i][j] = eye - a;
        __syncthreads();
        for (int k = 0; k < 16; ++k) {
            float f = Ms[i][k] / Ms[k][k];
            __syncthreads();
            if (i != k) {
                Ms[i][j] -= f * Ms[k][j];
                Rh[i][j] -= f * Rh[k][j];
            }
            __syncthreads();
        }
        float q = Rh[i][j] / Ms[i][i];
        float* dst = (m < 16) ? (QL + m * 256) : (QR + (m - 16) * 256);
        dst[i * 16 + j] = q;
    } else if (bid < PB_WC) {                 // ---- pack_wbg (384 blocks)
        const int row = bid - PB_WBG;
        ushort4 o = {0, 0, 0, 0};
        const float* src = nullptr;
        if (row < NSTATE) src = WB + (size_t)row * DIM;
        else if (row < NSTATE + 32) src = Wg + (size_t)(row - NSTATE) * DIM;
        if (src) {
            float4 v = *(const float4*)(src + t * 4);
            o.x = f2bf(v.x); o.y = f2bf(v.y); o.z = f2bf(v.z); o.w = f2bf(v.w);
        }
        *(ushort4*)(WBGb + (size_t)row * DIM + t * 4) = o;
    } else if (bid < PB_W1) {                 // ---- f2b WC (256 blocks)
        const int i = (bid - PB_WC) * 256 + t;     // covers DIM*NSTATE/4 exactly
        float4 v = *(const float4*)(WC + i * 4);
        ushort4 o;
        o.x = f2bf(v.x); o.y = f2bf(v.y); o.z = f2bf(v.z); o.w = f2bf(v.w);
        *(ushort4*)(WCb + i * 4) = o;
    } else if (bid < PB_W2) {                 // ---- padrow w1 (2816 blocks)
        const int row = bid - PB_W1;
        ushort4 o = {0, 0, 0, 0};
        if (row < DFF) {
            float4 v = *(const float4*)(w1 + (size_t)row * DIM + t * 4);
            o.x = f2bf(v.x); o.y = f2bf(v.y); o.z = f2bf(v.z); o.w = f2bf(v.w);
        }
        *(ushort4*)(w1p + (size_t)row * DIM + t * 4) = o;
    } else if (bid < PB_W3) {                 // ---- padrow w2 (2816 blocks)
        const int row = bid - PB_W2;
        ushort4 o = {0, 0, 0, 0};
        if (row < DFF) {
            float4 v = *(const float4*)(w2 + (size_t)row * DIM + t * 4);
            o.x = f2bf(v.x); o.y = f2bf(v.y); o.z = f2bf(v.z); o.w = f2bf(v.w);
        }
        *(ushort4*)(w2p + (size_t)row * DIM + t * 4) = o;
    } else if (bid < PB_RMS) {                // ---- pad_w3 (11264 blocks)
        const int lid = bid - PB_W3;
        const int row = lid / 11, cb = lid % 11;
        const int col = cb * 256 + t;
        if (col < DFFP) {
            ushort v = 0;
            if (col < DFF) v = f2bf(w3[(size_t)row * DFF + col]);
            w3p[(size_t)row * DFFP + col] = v;
        }
    } else {                                  // ---- rmsnorm1 (8192 blocks)
        __shared__ float part[4];
        __shared__ float invs;
        const int row = bid - PB_RMS;
        float4 xv = *(const float4*)(x + (size_t)row * DIM + t * 4);
        float ss = xv.x * xv.x + xv.y * xv.y + xv.z * xv.z + xv.w * xv.w;
        for (int off = 32; off > 0; off >>= 1) ss += __shfl_down(ss, off, 64);
        if ((t & 63) == 0) part[t >> 6] = ss;
        __syncthreads();
        if (t == 0) {
            float tot = part[0] + part[1] + part[2] + part[3];
            invs = 1.f / sqrtf(tot / (float)DIM + 1e-6f);
        }
        __syncthreads();
        float inv = invs;
        float4 wv = *(const float4*)(n1w + t * 4);
        ushort4 ov;
        ov.x = f2bf(wv.x * xv.x * inv);
        ov.y = f2bf(wv.y * xv.y * inv);
        ov.z = f2bf(wv.z * xv.z * inv);
        ov.w = f2bf(wv.w * xv.w * inv);
        *(ushort4*)(xs + (size_t)row * DIM + t * 4) = ov;
    }
}

// ---------------------------------------------------------------------------
// rmsnorm: out_bf16 = bf16(w * in / rms), fp32 input (norm2)
// ---------------------------------------------------------------------------
__global__ __launch_bounds__(256) void rms_kernel(
    const float* __restrict__ xin, const float* __restrict__ nw,
    ushort* __restrict__ xo)
{
    __shared__ float part[4];
    __shared__ float invs;
    const int row = blockIdx.x, t = threadIdx.x;
    float4 xv = *(const float4*)(xin + (size_t)row * DIM + t * 4);
    float ss = xv.x * xv.x + xv.y * xv.y + xv.z * xv.z + xv.w * xv.w;
    for (int off = 32; off > 0; off >>= 1) ss += __shfl_down(ss, off, 64);
    if ((t & 63) == 0) part[t >> 6] = ss;
    __syncthreads();
    if (t == 0) {
        float tot = part[0] + part[1] + part[2] + part[3];
        invs = 1.f / sqrtf(tot / (float)DIM + 1e-6f);
    }
    __syncthreads();
    float inv = invs;
    float4 wv = *(const float4*)(nw + t * 4);
    ushort4 ov;
    ov.x = f2bf(wv.x * xv.x * inv);
    ov.y = f2bf(wv.y * xv.y * inv);
    ov.z = f2bf(wv.z * xv.z * inv);
    ov.w = f2bf(wv.w * xv.w * inv);
    *(ushort4*)(xo + (size_t)row * DIM + t * 4) = ov;
}

// ---------------------------------------------------------------------------
// Windowed parallel scan. LC=8 -> 1024 blocks = 4/CU.
// One barrier/step: Hs deps are intra-wave; Us double-buffered; raw
// lgkmcnt+s_barrier avoids the vmcnt(0) drain.
// ---------------------------------------------------------------------------
__global__ __launch_bounds__(256) void scan_win_kernel(
    const float* __restrict__ QL, const float* __restrict__ QR,
    const float* __restrict__ gates, const float* __restrict__ Bx,
    ushort* __restrict__ hs)
{
    __shared__ float Hs[256];
    __shared__ float Us[2][256];
    const int chunk = blockIdx.x, b = blockIdx.y, t = threadIdx.x;
    const int hi = t >> 4, lo = t & 15;
    float Rrow[16], Lrow[16];
    #pragma unroll
    for (int k = 0; k < 16; ++k) {
        Rrow[k] = QR[hi * 256 + lo * 16 + k];   // R_Q[j=hi][i=lo][k]
        Lrow[k] = QL[lo * 256 + hi * 16 + k];   // L_Q[c=lo][r=hi][k]
    }
    Hs[t] = 0.f;
    __syncthreads();
    const int wstart = chunk * LC;
    const int s0 = (wstart >= WARM) ? (wstart - WARM) : 0;
    const int send = wstart + LC;
    const float* gb = gates + (size_t)b * S_LEN * 32;
    const float* xb = Bx + (size_t)b * S_LEN * NSTATE;
    ushort* hb = hs + (size_t)b * S_LEN * NSTATE;
    float beta  = gb[s0 * 32 + 16 + hi];
    float alpha = gb[s0 * 32 + lo];
    float bx    = xb[s0 * NSTATE + t];
    int q = 0;
    for (int s = s0; s < send; ++s) {
        float betaN = 0.f, alphaN = 0.f, bxN = 0.f;
        if (s + 1 < send) {
            betaN  = gb[(s + 1) * 32 + 16 + hi];
            alphaN = gb[(s + 1) * 32 + lo];
            bxN    = xb[(s + 1) * NSTATE + t];
        }
        float acc = 0.f;
        #pragma unroll
        for (int k = 0; k < 16; ++k) acc += Rrow[k] * Hs[hi * 16 + k];
        Us[q][t] = beta * acc;
        asm volatile("s_waitcnt lgkmcnt(0)" ::: "memory");
        __builtin_amdgcn_s_barrier();
        asm volatile("" ::: "memory");
        float acc2 = 0.f;
        #pragma unroll
        for (int k = 0; k < 16; ++k) acc2 += Lrow[k] * Us[q][k * 16 + lo];
        float h = alpha * acc2 + bx;
        Hs[t] = h;                       // intra-wave consumers only
        if (s >= wstart) hb[s * NSTATE + t] = f2bf(h);
        beta = betaN; alpha = alphaN; bx = bxN;
        q ^= 1;
    }
}

// ---------------------------------------------------------------------------
// Async GEMM: C(MxN) = A(MxK)*B(NxK)^T [+bias +resF] -> fp32.
// 128x128 tile, BK=64, XOR-8 LDS swizzle, 4 waves (2x2 of 64x64),
// 16x16x32 bf16 MFMA, global_load_lds width-16 staging.
// ---------------------------------------------------------------------------
__global__ __launch_bounds__(256) void gemm_async(
    const ushort* __restrict__ A, int lda,
    const ushort* __restrict__ B, int ldb,
    int K, int ldc,
    const float* __restrict__ bias,
    const float* __restrict__ resF,
    float* __restrict__ outF)
{
    __shared__ ushort As[128 * 64];
    __shared__ ushort Bs[128 * 64];
    const int tid = threadIdx.x;
    const int m0 = blockIdx.y * 128, n0 = blockIdx.x * 128;
    const int w = tid >> 6, lane = tid & 63;
    const int wm = (w >> 1) * 64, wn = (w & 1) * 64;
    const int lr = lane & 15, quad = lane >> 4;
    const int rx = lr & 7;   // reader XOR key (row&7 of every frag row)
    f32x4 acc[4][4];
    #pragma unroll
    for (int i = 0; i < 4; ++i)
        #pragma unroll
        for (int j = 0; j < 4; ++j) acc[i][j] = (f32x4){0.f, 0.f, 0.f, 0.f};
    const int srow = tid >> 3;                              // 0..31
    const int scol = (((tid & 7) ^ (srow & 7)) * 8);        // swizzled fetch col
    const ushort* ga = A + (size_t)(m0 + srow) * lda + scol;
    const ushort* gb = B + (size_t)(n0 + srow) * ldb + scol;
    for (int kt = 0; kt < K; kt += 64) {
        #pragma unroll
        for (int p = 0; p < 4; ++p) {
            gld_lds16(ga + (size_t)(p * 32) * lda + kt, &As[p * 2048 + tid * 8]);
            gld_lds16(gb + (size_t)(p * 32) * ldb + kt, &Bs[p * 2048 + tid * 8]);
        }
        __syncthreads();
        #pragma unroll
        for (int s = 0; s < 2; ++s) {
            const int cg = ((s * 4 + quad) ^ rx) * 8;
            bf16x8 af[4], bfr[4];
            #pragma unroll
            for (int f = 0; f < 4; ++f) {
                af[f]  = *(const bf16x8*)&As[(wm + f * 16 + lr) * 64 + cg];
                bfr[f] = *(const bf16x8*)&Bs[(wn + f * 16 + lr) * 64 + cg];
            }
            #pragma unroll
            for (int i = 0; i < 4; ++i)
                #pragma unroll
                for (int j = 0; j < 4; ++j)
                    acc[i][j] = __builtin_amdgcn_mfma_f32_16x16x32_bf16(
                        af[i], bfr[j], acc[i][j], 0, 0, 0);
        }
        __syncthreads();
    }
    #pragma unroll
    for (int i = 0; i < 4; ++i) {
        int row = m0 + wm + i * 16 + quad * 4;
        #pragma unroll
        for (int j = 0; j < 4; ++j) {
            int col = n0 + wn + j * 16 + lr;
            float bv = bias ? bias[col] : 0.f;
            #pragma unroll
            for (int r = 0; r < 4; ++r) {
                size_t idx = (size_t)(row + r) * ldc + col;
                float v = acc[i][j][r] + bv;
                if (resF) v += resF[idx];
                outF[idx] = v;
            }
        }
    }
}

// ---------------------------------------------------------------------------
// Merged Bx+gates GEMM: [Bx | gate-logits] = xs @ WBG^T, N=384, BK=64+swizzle.
// ---------------------------------------------------------------------------
__global__ __launch_bounds__(256) void gemm_bxg(
    const ushort* __restrict__ A,     // xs: NROWS x DIM
    const ushort* __restrict__ WBG,   // NBG x DIM
    const float* __restrict__ bB, const float* __restrict__ bg,
    float* __restrict__ Bx, float* __restrict__ gates)
{
    __shared__ ushort As[128 * 64];
    __shared__ ushort Bs[128 * 64];
    const int tid = threadIdx.x;
    const int m0 = blockIdx.y * 128, n0 = blockIdx.x * 128;
    const int w = tid >> 6, lane = tid & 63;
    const int wm = (w >> 1) * 64, wn = (w & 1) * 64;
    const int lr = lane & 15, quad = lane >> 4;
    const int rx = lr & 7;
    f32x4 acc[4][4];
    #pragma unroll
    for (int i = 0; i < 4; ++i)
        #pragma unroll
        for (int j = 0; j < 4; ++j) acc[i][j] = (f32x4){0.f, 0.f, 0.f, 0.f};
    const int srow = tid >> 3;
    const int scol = (((tid & 7) ^ (srow & 7)) * 8);
    const ushort* ga = A   + (size_t)(m0 + srow) * DIM + scol;
    const ushort* gb = WBG + (size_t)(n0 + srow) * DIM + scol;
    for (int kt = 0; kt < DIM; kt += 64) {
        #pragma unroll
        for (int p = 0; p < 4; ++p) {
            gld_lds16(ga + (size_t)(p * 32) * DIM + kt, &As[p * 2048 + tid * 8]);
            gld_lds16(gb + (size_t)(p * 32) * DIM + kt, &Bs[p * 2048 + tid * 8]);
        }
        __syncthreads();
        #pragma unroll
        for (int s = 0; s < 2; ++s) {
            const int cg = ((s * 4 + quad) ^ rx) * 8;
            bf16x8 af[4], bfr[4];
            #pragma unroll
            for (int f = 0; f < 4; ++f) {
                af[f]  = *(const bf16x8*)&As[(wm + f * 16 + lr) * 64 + cg];
                bfr[f] = *(const bf16x8*)&Bs[(wn + f * 16 + lr) * 64 + cg];
            }
            #pragma unroll
            for (int i = 0; i < 4; ++i)
                #pragma unroll
                for (int j = 0; j < 4; ++j)
                    acc[i][j] = __builtin_amdgcn_mfma_f32_16x16x32_bf16(
                        af[i], bfr[j], acc[i][j], 0, 0, 0);
        }
        __syncthreads();
    }
    #pragma unroll
    for (int i = 0; i < 4; ++i) {
        int row = m0 + wm + i * 16 + quad * 4;
        #pragma unroll
        for (int j = 0; j < 4; ++j) {
            int col = n0 + wn + j * 16 + lr;
            #pragma unroll
            for (int r = 0; r < 4; ++r) {
                float v = acc[i][j][r];
                if (col < NSTATE) {
                    Bx[(size_t)(row + r) * NSTATE + col] = v + bB[col];
                } else if (col < NSTATE + 32) {
                    int g = col - NSTATE;
                    gates[(size_t)(row + r) * 32 + g] =
                        1.f / (1.f + expf(-(v + bg[g])));
                }
            }
        }
    }
}

// ---------------------------------------------------------------------------
// Fused FFN GEMM: pb = bf16( silu(xn@w1^T) * (xn@w2^T) ), K-padded layout.
// BK=64 + XOR-8 swizzle; A staged once, two B tiles -> 64 MFMA per barrier
// round. [2-barrier structure = its structural ceiling at ~108us/875TF;
// 8-phase port abandoned after 3 attempts (r2 remat / r3 spills / r5
// LDS+barrier-bound).]
// ---------------------------------------------------------------------------
__global__ __launch_bounds__(256, 2) void ffn_gemm(
    const ushort* __restrict__ A,    // xn: NROWS x DIM
    const ushort* __restrict__ B1,   // w1p: DFQ x DIM
    const ushort* __restrict__ B2,   // w2p: DFQ x DIM
    ushort* __restrict__ pb)         // NROWS x DFFP
{
    __shared__ ushort As [128 * 64];
    __shared__ ushort B1s[128 * 64];
    __shared__ ushort B2s[128 * 64];
    const int tid = threadIdx.x;
    const int m0 = blockIdx.y * 128, n0 = blockIdx.x * 128;
    const int w = tid >> 6, lane = tid & 63;
    const int wm = (w >> 1) * 64, wn = (w & 1) * 64;
    const int lr = lane & 15, quad = lane >> 4;
    const int rx = lr & 7;
    f32x4 acc1[4][4], acc2[4][4];
    #pragma unroll
    for (int i = 0; i < 4; ++i)
        #pragma unroll
        for (int j = 0; j < 4; ++j) {
            acc1[i][j] = (f32x4){0.f, 0.f, 0.f, 0.f};
            acc2[i][j] = (f32x4){0.f, 0.f, 0.f, 0.f};
        }
    const int srow = tid >> 3;
    const int scol = (((tid & 7) ^ (srow & 7)) * 8);
    const ushort* ga  = A  + (size_t)(m0 + srow) * DIM + scol;
    const ushort* gb1 = B1 + (size_t)(n0 + srow) * DIM + scol;
    const ushort* gb2 = B2 + (size_t)(n0 + srow) * DIM + scol;
    for (int kt = 0; kt < DIM; kt += 64) {
        #pragma unroll
        for (int p = 0; p < 4; ++p) {
            gld_lds16(ga  + (size_t)(p * 32) * DIM + kt, &As [p * 2048 + tid * 8]);
            gld_lds16(gb1 + (size_t)(p * 32) * DIM + kt, &B1s[p * 2048 + tid * 8]);
            gld_lds16(gb2 + (size_t)(p * 32) * DIM + kt, &B2s[p * 2048 + tid * 8]);
        }
        __syncthreads();
        #pragma unroll
        for (int s = 0; s < 2; ++s) {
            const int cg = ((s * 4 + quad) ^ rx) * 8;
            bf16x8 af[4], b1f[4], b2f[4];
            #pragma unroll
            for (int f = 0; f < 4; ++f) {
                af[f]  = *(const bf16x8*)&As [(wm + f * 16 + lr) * 64 + cg];
                b1f[f] = *(const bf16x8*)&B1s[(wn + f * 16 + lr) * 64 + cg];
                b2f[f] = *(const bf16x8*)&B2s[(wn + f * 16 + lr) * 64 + cg];
            }
            #pragma unroll
            for (int i = 0; i < 4; ++i)
                #pragma unroll
                for (int j = 0; j < 4; ++j) {
                    acc1[i][j] = __builtin_amdgcn_mfma_f32_16x16x32_bf16(
                        af[i], b1f[j], acc1[i][j], 0, 0, 0);
                    acc2[i][j] = __builtin_amdgcn_mfma_f32_16x16x32_bf16(
                        af[i], b2f[j], acc2[i][j], 0, 0, 0);
                }
        }
        __syncthreads();
    }
    #pragma unroll
    for (int i = 0; i < 4; ++i) {
        int row = m0 + wm + i * 16 + quad * 4;
        #pragma unroll
        for (int j = 0; j < 4; ++j) {
            int col = n0 + wn + j * 16 + lr;
            if (col < DFFP) {
                #pragma unroll
                for (int r = 0; r < 4; ++r) {
                    float v1 = acc1[i][j][r];
                    float v2 = acc2[i][j][r];
                    float p = v1 / (1.f + expf(-v1)) * v2;
                    pb[(size_t)(row + r) * DFFP + col] = f2bf(p);
                }
            }
        }
    }
}

// ---------------------------------------------------------------------------
extern "C" void kernel_launch(void* const* d_in, const int* in_sizes, int n_in,
                              void* d_out, int out_size, void* d_ws, size_t ws_size,
                              hipStream_t stream) {
    const float* x   = (const float*)d_in[0];
    const float* Lsk = (const float*)d_in[1];
    const float* Rsk = (const float*)d_in[2];
    const float* Wg  = (const float*)d_in[3];
    const float* bg  = (const float*)d_in[4];
    const float* WB  = (const float*)d_in[5];
    const float* bB  = (const float*)d_in[6];
    const float* WC  = (const float*)d_in[7];
    const float* bC  = (const float*)d_in[8];
    const float* n1w = (const float*)d_in[9];
    const float* n2w = (const float*)d_in[10];
    const float* w1  = (const float*)d_in[11];
    const float* w2  = (const float*)d_in[12];
    const float* w3  = (const float*)d_in[13];
    float* out = (float*)d_out;

    char* wp = (char*)d_ws;
    auto carve = [&](size_t bytes) -> char* {
        char* p = wp;
        wp += (bytes + 255) & ~(size_t)255;
        return p;
    };
    float*  QL    = (float*)carve(16 * 256 * 4);
    float*  QR    = (float*)carve(16 * 256 * 4);
    ushort* WBGb  = (ushort*)carve((size_t)NBG * DIM * 2);
    ushort* WCb   = (ushort*)carve((size_t)DIM * NSTATE * 2);
    ushort* w1p   = (ushort*)carve((size_t)DFQ * DIM * 2);
    ushort* w2p   = (ushort*)carve((size_t)DFQ * DIM * 2);
    ushort* w3p   = (ushort*)carve((size_t)DIM * DFFP * 2);
    ushort* xs    = (ushort*)carve((size_t)NROWS * DIM * 2);
    float*  x2    = (float*)carve((size_t)NROWS * DIM * 4);
    ushort* pb    = (ushort*)carve((size_t)NROWS * DFFP * 2);
    char*   scr   = carve((size_t)16 << 20);                // gates/Bx/hs region
    float*  gates = (float*)scr;                            // 1.05 MB
    float*  Bx    = (float*)(scr + (1 << 21));              // 8.39 MB @ +2MB
    ushort* hs    = (ushort*)(scr + (11u << 20));           // 4.19 MB @ +11MB
    ushort* xn    = xs;   // xs dead after bxg GEMM; reuse as xn

    // all weight prep + cayley + rmsnorm1 in ONE launch
    prep_kernel<<<PB_TOTAL, 256, 0, stream>>>(
        Lsk, Rsk, QL, QR, WB, Wg, WBGb, WC, WCb,
        w1, w1p, w2, w2p, w3, w3p, x, n1w, xs);
    // [Bx | gates] = xs @ WBG^T (+bB | sigmoid(+bg))
    gemm_bxg<<<dim3(3, 64), 256, 0, stream>>>(xs, WBGb, bB, bg, Bx, gates);
    scan_win_kernel<<<dim3(S_LEN / LC, BATCH), 256, 0, stream>>>(QL, QR, gates, Bx, hs);
    // x2 = hs @ WC^T + bC + x  -> fp32
    gemm_async<<<dim3(8, 64), 256, 0, stream>>>(hs, NSTATE, WCb, NSTATE, NSTATE, DIM,
                                                bC, x, x2);
    // xn = rmsnorm(x2, n2w)
    rms_kernel<<<NROWS, 256, 0, stream>>>(x2, n2w, xn);
    // pb = silu(xn@w1^T) * (xn@w2^T)  (fused, K-padded bf16 out)
    ffn_gemm<<<dim3(DFQ / 128, 64), 256, 0, stream>>>(xn, w1p, w2p, pb);
    // out = pb @ w3p^T + x2  -> fp32 (d_out)
    gemm_async<<<dim3(8, 64), 256, 0, stream>>>(pb, DFFP, w3p, DFFP, DFFP, DIM,
                                                nullptr, x2, out);
}